// Round 8
// baseline (983.342 us; speedup 1.0000x reference)
//
#include <hip/hip_runtime.h>
#include <math.h>

#define EPS 1e-5f

typedef __attribute__((ext_vector_type(8))) short short8;
typedef __attribute__((ext_vector_type(4))) float floatx4;

typedef __attribute__((address_space(1))) const void* gas1_t;
typedef __attribute__((address_space(3))) void* las3_t;

__device__ __forceinline__ void glls16(const void* g, void* l) {
    __builtin_amdgcn_global_load_lds((gas1_t)g, (las3_t)l, 16, 0, 0);
}

__device__ __forceinline__ float mishf(float x) {
    float sp = fmaxf(x, 0.0f) + log1pf(expf(-fabsf(x)));
    return x * tanhf(sp);
}
__device__ __forceinline__ unsigned short f2bf(float f) {
    unsigned int u = __float_as_uint(f);
    unsigned int r = (u + 0x7fffu + ((u >> 16) & 1u)) >> 16;
    return (unsigned short)r;
}
__device__ __forceinline__ float bf2f(unsigned short s) {
    return __uint_as_float(((unsigned int)s) << 16);
}
__device__ __forceinline__ unsigned int pk2(unsigned short a, unsigned short b) {
    return (unsigned int)a | ((unsigned int)b << 16);
}

// ================= fused setup: weight packs, cvt, mish, zero pads, lnc ====
// R7: lnc_k merged (blocks 9056..13983); cnb moved to non-overlapping region.
__global__ __launch_bounds__(256) void setup_k(
        const float* __restrict__ conv0_w, const float* __restrict__ conv1_w,
        const float* __restrict__ res_w, const float* __restrict__ q_w,
        const float* __restrict__ k_w, const float* __restrict__ v_w,
        const float* __restrict__ t,
        const float* __restrict__ cond,
        const float* __restrict__ lncg, const float* __restrict__ lncb,
        const int* __restrict__ cidx,
        unsigned short* __restrict__ wp0, unsigned short* __restrict__ wp1,
        unsigned short* __restrict__ wr, unsigned short* __restrict__ wq,
        unsigned short* __restrict__ wk, unsigned short* __restrict__ wvv,
        float* __restrict__ mt,
        unsigned short* __restrict__ xTp, unsigned short* __restrict__ h0Tp,
        unsigned short* __restrict__ cn) {
    __shared__ float r1[4], r2[4], mv[2];
    const int blk = blockIdx.x, tid = threadIdx.x;
    if (blk < 2560) {                       // pack conv0_w -> wp0 [kk][co][ci]
        int o = blk * 256 + tid;
        int ci = o & 255, co = (o >> 8) & 511, kk = o >> 17;
        wp0[o] = f2bf(conv0_w[((size_t)co * 256 + ci) * 5 + kk]);
    } else if (blk < 7680) {                // pack conv1_w -> wp1
        int o = (blk - 2560) * 256 + tid;
        int ci = o & 511, co = (o >> 9) & 511, kk = o >> 18;
        wp1[o] = f2bf(conv1_w[((size_t)co * 512 + ci) * 5 + kk]);
    } else if (blk < 7808) {                // res_w cvt
        int i = (blk - 7680) * 256 + tid;
        float4 f = *(const float4*)&res_w[(size_t)i * 4];
        *(uint2*)&wr[(size_t)i * 4] =
            make_uint2(pk2(f2bf(f.x), f2bf(f.y)), pk2(f2bf(f.z), f2bf(f.w)));
    } else if (blk < 8064) {                // q_w cvt
        int i = (blk - 7808) * 256 + tid;
        float4 f = *(const float4*)&q_w[(size_t)i * 4];
        *(uint2*)&wq[(size_t)i * 4] =
            make_uint2(pk2(f2bf(f.x), f2bf(f.y)), pk2(f2bf(f.z), f2bf(f.w)));
    } else if (blk < 8448) {                // k_w cvt
        int i = (blk - 8064) * 256 + tid;
        float4 f = *(const float4*)&k_w[(size_t)i * 4];
        *(uint2*)&wk[(size_t)i * 4] =
            make_uint2(pk2(f2bf(f.x), f2bf(f.y)), pk2(f2bf(f.z), f2bf(f.w)));
    } else if (blk < 8832) {                // v_w cvt
        int i = (blk - 8448) * 256 + tid;
        float4 f = *(const float4*)&v_w[(size_t)i * 4];
        *(uint2*)&wvv[(size_t)i * 4] =
            make_uint2(pk2(f2bf(f.x), f2bf(f.y)), pk2(f2bf(f.z), f2bf(f.w)));
    } else if (blk < 8960) {                // mish(t)
        int i = (blk - 8832) * 256 + tid;
        mt[i] = mishf(t[i]);
    } else if (blk < 8992) {                // zero xTp pad rows
        int idx = (blk - 8960) * 256 + tid;     // 8192 uint4 stores
        int u = idx * 8;
        int c = u & 255, r4 = (u >> 8) & 3, b = u >> 10;
        int row = (r4 < 2) ? r4 : (512 + r4);
        *(uint4*)&xTp[((size_t)b * 516 + row) * 256 + c] = make_uint4(0, 0, 0, 0);
    } else if (blk < 9056) {                // zero h0Tp pad rows
        int idx = (blk - 8992) * 256 + tid;     // 16384 uint4 stores
        int u = idx * 8;
        int c = u & 511, r4 = (u >> 9) & 3, b = u >> 11;
        int row = (r4 < 2) ? r4 : (512 + r4);
        *(uint4*)&h0Tp[((size_t)b * 516 + row) * 512 + c] = make_uint4(0, 0, 0, 0);
    } else {                                // lnc: LayerNorm cond rows -> cnb
        int bn = blk - 9056;
        int b = bn / 77, n = bn - b * 77;
        int ib = cidx[b];
        const float* src = cond + ((size_t)ib * 77 + n) * 768;
        float v[3];
        float s = 0.f, s2 = 0.f;
#pragma unroll
        for (int i = 0; i < 3; ++i) {
            v[i] = src[tid + i * 256];
            s += v[i]; s2 += v[i] * v[i];
        }
#pragma unroll
        for (int o = 32; o > 0; o >>= 1) {
            s += __shfl_xor(s, o, 64);
            s2 += __shfl_xor(s2, o, 64);
        }
        if ((tid & 63) == 0) { r1[tid >> 6] = s; r2[tid >> 6] = s2; }
        __syncthreads();
        if (tid == 0) {
            float ts = r1[0] + r1[1] + r1[2] + r1[3];
            float ts2 = r2[0] + r2[1] + r2[2] + r2[3];
            float m = ts * (1.f / 768.f);
            float var = ts2 * (1.f / 768.f) - m * m;
            mv[0] = m; mv[1] = rsqrtf(var + EPS);
        }
        __syncthreads();
        float m = mv[0], rs = mv[1];
        unsigned short* dst = cn + ((size_t)b * 77 + n) * 768;
#pragma unroll
        for (int i = 0; i < 3; ++i) {
            int c = tid + i * 256;
            dst[c] = f2bf((v[i] - m) * rs * lncg[c] + lncb[c]);
        }
    }
}

// ------------- x [b][ci][l] fp32 -> xTp [b][516][256] bf16 (rows 2..513)
__global__ __launch_bounds__(256) void xpose_cvt(const float* __restrict__ x,
        unsigned short* __restrict__ xT) {
    __shared__ float tile[64][68];
    const int tid = threadIdx.x;
    const int l0 = blockIdx.x * 64, c0 = blockIdx.y * 64, b = blockIdx.z;
    for (int idx = tid; idx < 64 * 16; idx += 256) {
        int cr = idx >> 4, lc = (idx & 15) * 4;
        float4 f = *(const float4*)&x[((size_t)b * 256 + c0 + cr) * 512 + l0 + lc];
        tile[cr][lc] = f.x; tile[cr][lc + 1] = f.y;
        tile[cr][lc + 2] = f.z; tile[cr][lc + 3] = f.w;
    }
    __syncthreads();
    for (int idx = tid; idx < 64 * 16; idx += 256) {
        int lr = idx >> 4, cc = (idx & 15) * 4;
        *(uint2*)&xT[((size_t)b * 516 + 2 + l0 + lr) * 256 + c0 + cc] =
            make_uint2(pk2(f2bf(tile[cc][lr]), f2bf(tile[cc + 1][lr])),
                       pk2(f2bf(tile[cc + 2][lr]), f2bf(tile[cc + 3][lr])));
    }
}

// ------------------------------------------- fp32 NT GEMM (ss only, tiny)
template<int KD>
__global__ __launch_bounds__(256) void gemm_nt(const float* __restrict__ A,
        const float* __restrict__ W, const float* __restrict__ bias,
        float* __restrict__ C, int M, int N) {
    constexpr int ST = 20;
    __shared__ __align__(16) float As[64 * ST];
    __shared__ __align__(16) float Ws[64 * ST];
    const int tid = threadIdx.x;
    const int r0 = blockIdx.x * 64, c0 = blockIdx.y * 64;
    const int tx = tid & 15, ty = tid >> 4;
    const int lrow = tid >> 2, lk = (tid & 3) * 4;
    float acc[4][4];
#pragma unroll
    for (int i = 0; i < 4; ++i)
#pragma unroll
        for (int j = 0; j < 4; ++j) acc[i][j] = 0.f;
    for (int k0 = 0; k0 < KD; k0 += 16) {
        __syncthreads();
        *(float4*)&As[lrow * ST + lk] =
            *(const float4*)&A[(size_t)(r0 + lrow) * KD + k0 + lk];
        *(float4*)&Ws[lrow * ST + lk] =
            *(const float4*)&W[(size_t)(c0 + lrow) * KD + k0 + lk];
        __syncthreads();
#pragma unroll
        for (int kk = 0; kk < 16; kk += 4) {
            float4 av[4], wv[4];
#pragma unroll
            for (int i = 0; i < 4; ++i)
                av[i] = *(const float4*)&As[(ty + 16 * i) * ST + kk];
#pragma unroll
            for (int j = 0; j < 4; ++j)
                wv[j] = *(const float4*)&Ws[(tx + 16 * j) * ST + kk];
#pragma unroll
            for (int i = 0; i < 4; ++i)
#pragma unroll
                for (int j = 0; j < 4; ++j) {
                    acc[i][j] = fmaf(av[i].x, wv[j].x, acc[i][j]);
                    acc[i][j] = fmaf(av[i].y, wv[j].y, acc[i][j]);
                    acc[i][j] = fmaf(av[i].z, wv[j].z, acc[i][j]);
                    acc[i][j] = fmaf(av[i].w, wv[j].w, acc[i][j]);
                }
        }
    }
#pragma unroll
    for (int j = 0; j < 4; ++j) {
        int c = c0 + tx + 16 * j;
        float bv = bias[c];
#pragma unroll
        for (int i = 0; i < 4; ++i)
            C[(size_t)(r0 + ty + 16 * i) * N + c] = acc[i][j] + bv;
    }
}

// ====== MFMA conv (KS=5), padded input, prefetch double-buffer, fused GN ===
// R7: XCD-grouping swizzle (T1). 1D grid 1024; the 8 co-blocks sharing one
// X-tile get ids == const (mod 8) -> same XCD -> X staged into ONE L2
// instead of 4 (default round-robin spread). Loop structure = R1-exact.
template<int CI, bool FILM, bool OPAD>
__global__ __launch_bounds__(256) void conv5_mfma(
        const unsigned short* __restrict__ xb,
        const unsigned short* __restrict__ wp,
        const float* __restrict__ bias,
        const float* __restrict__ gam, const float* __restrict__ bet,
        const float* __restrict__ ss,
        unsigned short* __restrict__ outT) {
    constexpr int NC = CI / 32;
    __shared__ __align__(16) unsigned short xs[2][260 * 32];
    __shared__ __align__(16) unsigned short wsm[2][5 * 64 * 32];
    __shared__ float sgam[64], sbet[64], sbias[64], sscale[64], sshift[64];

    const int tid = threadIdx.x;
    // ---- XCD-grouping swizzle: group = (l0,b) [8 co-members share X-tile]
    const int id = blockIdx.x;               // 0..1023
    const int sN = id >> 3;                  // 0..127
    const int grp = ((id & 7) << 4) + (sN >> 3);   // 0..127  (bijective)
    const int l0 = (grp & 1) * 256;
    const int b = grp >> 1;
    const int co0 = (sN & 7) * 64;
    const int lane = tid & 63;
    const int wv = tid >> 6;
    const int lq = lane & 15, qd = lane >> 4;
    const int wn = wv * 64;

    if (tid < 64) {
        int co = co0 + tid;
        sbias[tid] = bias[co];
        sgam[tid] = gam[co];
        sbet[tid] = bet[co];
        if (FILM) {
            sscale[tid] = ss[(size_t)b * 1024 + co];
            sshift[tid] = ss[(size_t)b * 1024 + 512 + co];
        }
    }

    const unsigned short* gxb = xb + ((size_t)b * 516 + l0) * CI;
    const unsigned short* gwb = wp + (size_t)co0 * CI;

    // ---- staging pointers; advance +32 shorts per chunk
    const unsigned short* xsp[5];
    const unsigned short* wsp[5];
    unsigned sdo[5];
#pragma unroll
    for (int it = 0; it < 5; ++it) {
        int task = it * 256 + tid;
        {
            int ri = task >> 2, pos = task & 3;
            int seg = pos ^ ((ri >> 1) & 3);
            xsp[it] = gxb + (size_t)ri * CI + seg * 8;
        }
        {
            int kk = task >> 8, r = task & 255;
            int col = r >> 2, pos = r & 3;
            int seg = pos ^ ((col >> 1) & 3);
            wsp[it] = gwb + ((size_t)kk * 512 + col) * CI + seg * 8;
        }
        sdo[it] = (unsigned)(it * 256 + wn) * 8;
    }
    const bool xv4 = tid < 16;   // only x-stage it==4 is partially valid

    auto stage = [&](int buf) {
#pragma unroll
        for (int it = 0; it < 5; ++it) {
            if (it < 4 || xv4) glls16(xsp[it], &xs[buf][sdo[it]]);
            xsp[it] += 32;
        }
#pragma unroll
        for (int it = 0; it < 5; ++it) {
            glls16(wsp[it], &wsm[buf][sdo[it]]);
            wsp[it] += 32;
        }
    };

    // ---- precomputed LDS fragment byte offsets (loop-invariant)
    unsigned bvo[5][4], avo[5][4];
#pragma unroll
    for (int kk = 0; kk < 5; ++kk) {
#pragma unroll
        for (int j = 0; j < 4; ++j) {
            int row = wn + j * 16 + lq + kk;
            int pos = qd ^ ((row >> 1) & 3);
            bvo[kk][j] = (unsigned)(row * 32 + pos * 8) * 2u;
        }
#pragma unroll
        for (int i = 0; i < 4; ++i) {
            int crow = i * 16 + lq;
            int pos = qd ^ ((crow >> 1) & 3);
            avo[kk][i] = (unsigned)(kk * 2048 + crow * 32 + pos * 8) * 2u;
        }
    }

    floatx4 acc[4][4];
#pragma unroll
    for (int i = 0; i < 4; ++i)
#pragma unroll
        for (int j = 0; j < 4; ++j) acc[i][j] = (floatx4){0.f, 0.f, 0.f, 0.f};

    auto compute = [&](int buf) {
        const char* xr = (const char*)xs[buf];
        const char* wr_ = (const char*)wsm[buf];
#pragma unroll
        for (int kk = 0; kk < 5; ++kk) {
            short8 bvf[4];
#pragma unroll
            for (int j = 0; j < 4; ++j)
                bvf[j] = *(const short8*)(xr + bvo[kk][j]);
#pragma unroll
            for (int i = 0; i < 4; ++i) {
                short8 av = *(const short8*)(wr_ + avo[kk][i]);
#pragma unroll
                for (int j = 0; j < 4; ++j)
                    acc[i][j] = __builtin_amdgcn_mfma_f32_16x16x32_bf16(
                        av, bvf[j], acc[i][j], 0, 0, 0);
            }
        }
    };

    stage(0);
    __syncthreads();
#pragma unroll 1
    for (int c = 0; c < NC; c += 2) {
        stage(1);
        compute(0);
        __syncthreads();
        if (c + 2 < NC) stage(0);
        compute(1);
        __syncthreads();
    }

    // ---- fused epilogue: bias, GN stats over 64 co per l, FiLM, mish, bf16
    float m_[4], rs_[4];
#pragma unroll
    for (int j = 0; j < 4; ++j) {
        float s1 = 0.f, s2 = 0.f;
#pragma unroll
        for (int i = 0; i < 4; ++i) {
            float4 bv4 = *(const float4*)&sbias[i * 16 + qd * 4];
            float ba[4] = {bv4.x, bv4.y, bv4.z, bv4.w};
#pragma unroll
            for (int r = 0; r < 4; ++r) {
                float v = acc[i][j][r] + ba[r];
                acc[i][j][r] = v;
                s1 += v; s2 += v * v;
            }
        }
        s1 += __shfl_xor(s1, 16, 64); s2 += __shfl_xor(s2, 16, 64);
        s1 += __shfl_xor(s1, 32, 64); s2 += __shfl_xor(s2, 32, 64);
        float mean = s1 * (1.f / 64.f);
        float var = s2 * (1.f / 64.f) - mean * mean;
        m_[j] = mean; rs_[j] = rsqrtf(var + EPS);
    }
#pragma unroll
    for (int j = 0; j < 4; ++j) {
        int l = l0 + wn + j * 16 + lq;
        size_t rowbase = OPAD ? (((size_t)b * 516 + 2 + l) * 512 + co0)
                              : (((size_t)b * 512 + l) * 512 + co0);
#pragma unroll
        for (int i = 0; i < 4; ++i) {
            float4 g4 = *(const float4*)&sgam[i * 16 + qd * 4];
            float4 b4 = *(const float4*)&sbet[i * 16 + qd * 4];
            float ga[4] = {g4.x, g4.y, g4.z, g4.w};
            float be[4] = {b4.x, b4.y, b4.z, b4.w};
            float sa[4] = {0, 0, 0, 0}, sh[4] = {0, 0, 0, 0};
            if (FILM) {
                float4 s4 = *(const float4*)&sscale[i * 16 + qd * 4];
                float4 h4 = *(const float4*)&sshift[i * 16 + qd * 4];
                sa[0] = s4.x; sa[1] = s4.y; sa[2] = s4.z; sa[3] = s4.w;
                sh[0] = h4.x; sh[1] = h4.y; sh[2] = h4.z; sh[3] = h4.w;
            }
            unsigned short o[4];
#pragma unroll
            for (int r = 0; r < 4; ++r) {
                float v = (acc[i][j][r] - m_[j]) * rs_[j] * ga[r] + be[r];
                if (FILM) v = v * (1.f + sa[r]) + sh[r];
                o[r] = f2bf(mishf(v));
            }
            *(uint2*)&outT[rowbase + i * 16 + qd * 4] =
                make_uint2(pk2(o[0], o[1]), pk2(o[2], o[3]));
        }
    }
}

// ====== generic MFMA GEMM, prefetch double-buffer =========================
// EPI 0=RES(add h1T dense, write outTb bf16); 1=QSM(softmax/head); 2=KV fp32
// PADA: A rows live in [b][516][KD] at row 2+t
// EPI==2 supports merged dual-weight dispatch via blockIdx.z.
template<int KD, int EPI, bool PADA>
__global__ __launch_bounds__(256) void gemm1_mfma(
        const unsigned short* __restrict__ A,
        const unsigned short* __restrict__ W,
        const float* __restrict__ bias,
        const unsigned short* __restrict__ W2,
        const float* __restrict__ bias2,
        const unsigned short* __restrict__ addT,
        float* __restrict__ outF,
        float* __restrict__ outF2,
        unsigned short* __restrict__ outB,
        int Mreal) {
    constexpr int NC = KD / 32;
    __shared__ __align__(16) unsigned short xs[2][256 * 32];
    __shared__ __align__(16) unsigned short wsm[2][64 * 32];
    __shared__ float sbias[64];
    const int tid = threadIdx.x;
    const int m0 = blockIdx.x * 256;
    const int n0 = blockIdx.y * 64;
    const int lane = tid & 63;
    const int wv = tid >> 6;
    const int lq = lane & 15, qd = lane >> 4;
    const int wn = wv * 64;

    const unsigned short* Wu = W;
    const float* biasu = bias;
    float* outFu = outF;
    if (EPI == 2 && blockIdx.z == 1) { Wu = W2; biasu = bias2; outFu = outF2; }

    if (tid < 64) sbias[tid] = biasu[n0 + tid];

    const size_t arow0 = PADA ? ((size_t)(m0 >> 9) * 516 + 2 + (m0 & 511))
                              : (size_t)m0;
    const unsigned short* gA = A + arow0 * KD;
    const unsigned short* gW = Wu + (size_t)n0 * KD;

    // ---- precomputed staging pointers
    const unsigned short* xp[4];
#pragma unroll
    for (int it = 0; it < 4; ++it) {
        int task = it * 256 + tid;
        int ri = task >> 2, pos = task & 3;
        int seg = pos ^ ((ri >> 1) & 3);
        xp[it] = gA + (size_t)ri * KD + seg * 8;
    }
    const unsigned short* wpq;
    {
        int col = tid >> 2, pos = tid & 3;
        int seg = pos ^ ((col >> 1) & 3);
        wpq = gW + (size_t)col * KD + seg * 8;
    }

    auto stage = [&](int buf) {
#pragma unroll
        for (int it = 0; it < 4; ++it) {
            glls16(xp[it], &xs[buf][(unsigned)(it * 256 + wn) * 8]);
            xp[it] += 32;
        }
        glls16(wpq, &wsm[buf][(unsigned)wn * 8]);
        wpq += 32;
    };

    // ---- precomputed LDS fragment byte offsets
    unsigned bvo[4], avo[4];
#pragma unroll
    for (int j = 0; j < 4; ++j) {
        int row = wn + j * 16 + lq;
        int pos = qd ^ ((row >> 1) & 3);
        bvo[j] = (unsigned)(row * 32 + pos * 8) * 2u;
    }
#pragma unroll
    for (int i = 0; i < 4; ++i) {
        int crow = i * 16 + lq;
        int pos = qd ^ ((crow >> 1) & 3);
        avo[i] = (unsigned)(crow * 32 + pos * 8) * 2u;
    }

    floatx4 acc[4][4];
#pragma unroll
    for (int i = 0; i < 4; ++i)
#pragma unroll
        for (int j = 0; j < 4; ++j) acc[i][j] = (floatx4){0.f, 0.f, 0.f, 0.f};

    auto compute = [&](int buf) {
        const char* xr = (const char*)xs[buf];
        const char* wr_ = (const char*)wsm[buf];
        short8 bvf[4];
#pragma unroll
        for (int j = 0; j < 4; ++j)
            bvf[j] = *(const short8*)(xr + bvo[j]);
#pragma unroll
        for (int i = 0; i < 4; ++i) {
            short8 av = *(const short8*)(wr_ + avo[i]);
#pragma unroll
            for (int j = 0; j < 4; ++j)
                acc[i][j] = __builtin_amdgcn_mfma_f32_16x16x32_bf16(
                    av, bvf[j], acc[i][j], 0, 0, 0);
        }
    };

    stage(0);
    __syncthreads();
#pragma unroll 1
    for (int c = 0; c < NC; c += 2) {
        stage(1);
        compute(0);
        __syncthreads();
        if (c + 2 < NC) stage(0);
        compute(1);
        __syncthreads();
    }

#pragma unroll
    for (int i = 0; i < 4; ++i) {
        float4 bv4 = *(const float4*)&sbias[i * 16 + qd * 4];
        float ba[4] = {bv4.x, bv4.y, bv4.z, bv4.w};
#pragma unroll
        for (int j = 0; j < 4; ++j)
#pragma unroll
            for (int r = 0; r < 4; ++r) acc[i][j][r] += ba[r];
    }
    if (EPI == 0) {  // RES
#pragma unroll
        for (int j = 0; j < 4; ++j) {
            int m = m0 + wn + j * 16 + lq;
#pragma unroll
            for (int i = 0; i < 4; ++i) {
                int n = n0 + i * 16 + qd * 4;
                uint2 hv = *(const uint2*)&addT[(size_t)m * 512 + n];
                float vr[4];
                vr[0] = acc[i][j][0] + bf2f((unsigned short)(hv.x & 0xffff));
                vr[1] = acc[i][j][1] + bf2f((unsigned short)(hv.x >> 16));
                vr[2] = acc[i][j][2] + bf2f((unsigned short)(hv.y & 0xffff));
                vr[3] = acc[i][j][3] + bf2f((unsigned short)(hv.y >> 16));
                *(uint2*)&outB[(size_t)m * 512 + n] =
                    make_uint2(pk2(f2bf(vr[0]), f2bf(vr[1])),
                               pk2(f2bf(vr[2]), f2bf(vr[3])));
            }
        }
    } else if (EPI == 1) {  // QSM
#pragma unroll
        for (int j = 0; j < 4; ++j) {
            float mx = -3.4e38f;
#pragma unroll
            for (int i = 0; i < 4; ++i)
#pragma unroll
                for (int r = 0; r < 4; ++r) mx = fmaxf(mx, acc[i][j][r]);
            mx = fmaxf(mx, __shfl_xor(mx, 16, 64));
            mx = fmaxf(mx, __shfl_xor(mx, 32, 64));
            float s = 0.f;
#pragma unroll
            for (int i = 0; i < 4; ++i)
#pragma unroll
                for (int r = 0; r < 4; ++r) {
                    float e = expf(acc[i][j][r] - mx);
                    acc[i][j][r] = e; s += e;
                }
            s += __shfl_xor(s, 16, 64);
            s += __shfl_xor(s, 32, 64);
            float inv = 1.f / s;
            int m = m0 + wn + j * 16 + lq;
#pragma unroll
            for (int i = 0; i < 4; ++i) {
                *(uint2*)&outB[(size_t)m * 512 + n0 + i * 16 + qd * 4] =
                    make_uint2(pk2(f2bf(acc[i][j][0] * inv), f2bf(acc[i][j][1] * inv)),
                               pk2(f2bf(acc[i][j][2] * inv), f2bf(acc[i][j][3] * inv)));
            }
        }
    } else {  // KV
#pragma unroll
        for (int j = 0; j < 4; ++j) {
            int m = m0 + wn + j * 16 + lq;
            if (m < Mreal) {
#pragma unroll
                for (int i = 0; i < 4; ++i) {
                    float4 o = {acc[i][j][0], acc[i][j][1], acc[i][j][2], acc[i][j][3]};
                    *(float4*)&outFu[(size_t)m * 512 + n0 + i * 16 + qd * 4] = o;
                }
            }
        }
    }
}

// ---------- row LayerNorm of outTb[cidx[b]] (512 bf16) -> xlnT bf16
__global__ __launch_bounds__(256) void lnrow(const unsigned short* __restrict__ src,
        const float* __restrict__ g, const float* __restrict__ be,
        const int* __restrict__ cidx, unsigned short* __restrict__ dst) {
    const int tid = threadIdx.x;
    const int lane = tid & 63, wv = tid >> 6;
    const int row0 = blockIdx.x * 32 + wv * 8;
    for (int rr = 0; rr < 8; ++rr) {
        int m = row0 + rr;
        int b = m >> 9, t = m & 511;
        int ib = cidx[b];
        const unsigned short* sp = &src[((size_t)ib * 512 + t) * 512 + lane * 8];
        short8 u = *(const short8*)sp;
        float v[8];
        float s1 = 0.f, s2 = 0.f;
#pragma unroll
        for (int k = 0; k < 8; ++k) {
            v[k] = bf2f(((const unsigned short*)&u)[k]);
            s1 += v[k]; s2 += v[k] * v[k];
        }
#pragma unroll
        for (int o = 32; o > 0; o >>= 1) {
            s1 += __shfl_xor(s1, o, 64);
            s2 += __shfl_xor(s2, o, 64);
        }
        float mean = s1 * (1.f / 512.f);
        float var = s2 * (1.f / 512.f) - mean * mean;
        float rs = rsqrtf(var + EPS);
        float4 g0 = *(const float4*)&g[lane * 8];
        float4 g1 = *(const float4*)&g[lane * 8 + 4];
        float4 b0 = *(const float4*)&be[lane * 8];
        float4 b1 = *(const float4*)&be[lane * 8 + 4];
        float ga[8] = {g0.x, g0.y, g0.z, g0.w, g1.x, g1.y, g1.z, g1.w};
        float ba[8] = {b0.x, b0.y, b0.z, b0.w, b1.x, b1.y, b1.z, b1.w};
        unsigned short o8[8];
#pragma unroll
        for (int k = 0; k < 8; ++k)
            o8[k] = f2bf((v[k] - mean) * rs * ga[k] + ba[k]);
        *(uint4*)&dst[(size_t)m * 512 + lane * 8] =
            make_uint4(pk2(o8[0], o8[1]), pk2(o8[2], o8[3]),
                       pk2(o8[4], o8[5]), pk2(o8[6], o8[7]));
    }
}

// ---- FUSED attn + final: per (b,h) recompute attn tile in LDS, then
// out[ib, c, t] = bf2f(resT[..]) + (q @ attnT). Removes attn_k dispatch.
__global__ __launch_bounds__(256) void yattn_fused(
        const unsigned short* __restrict__ q,
        const float* __restrict__ k, const float* __restrict__ v,
        const unsigned short* __restrict__ resT,
        const int* __restrict__ cidx, float* __restrict__ out) {
    constexpr int NS = 68;
    constexpr int AS = 72;   // att tile row stride (bf16): 144B, 16B-aligned
    __shared__ __align__(16) float ks[77 * NS];
    __shared__ __align__(16) float vs[77 * NS];
    __shared__ float red[2][256];
    __shared__ __align__(16) unsigned short att[64 * AS];
    const int tid = threadIdx.x;
    const int h = blockIdx.y, b = blockIdx.z;
    const int ib = cidx[b];

    // ---- phase 1: stage K/V head slice (fp32)
    for (int idx = tid; idx < 77 * 16; idx += 256) {
        int n = idx >> 4, dq2 = (idx & 15) * 4;
        *(float4*)&ks[n * NS + dq2] =
            *(const float4*)&k[((size_t)b * 77 + n) * 512 + h * 64 + dq2];
        *(float4*)&vs[n * NS + dq2] =
            *(const float4*)&v[((size_t)b * 77 + n) * 512 + h * 64 + dq2];
    }
    __syncthreads();
    // ---- phase 2: fused k-softmax over n per d column (4 threads/column)
    {
        const int d = tid & 63, grp = tid >> 6;
        float mx = -3.4e38f;
        for (int n = grp; n < 77; n += 4) mx = fmaxf(mx, ks[n * NS + d]);
        red[0][grp * 64 + d] = mx;
        __syncthreads();
        mx = fmaxf(fmaxf(red[0][d], red[0][64 + d]),
                   fmaxf(red[0][128 + d], red[0][192 + d]));
        float s = 0.f;
        for (int n = grp; n < 77; n += 4) {
            float e = expf(ks[n * NS + d] - mx);
            ks[n * NS + d] = e; s += e;
        }
        red[1][grp * 64 + d] = s;
        __syncthreads();
        float inv = 1.f / (red[1][d] + red[1][64 + d] + red[1][128 + d] + red[1][192 + d]);
        for (int n = grp; n < 77; n += 4) ks[n * NS + d] *= inv;
    }
    __syncthreads();
    // ---- phase 3: attn tile [e][d] = sum_n ksm[n][d] * v[n][e] -> LDS bf16
    {
        const int e = tid & 63, dq = tid >> 6;
        float acc1[16];
#pragma unroll
        for (int u = 0; u < 16; ++u) acc1[u] = 0.f;
        for (int n = 0; n < 77; ++n) {
            float vv = vs[n * NS + e];
#pragma unroll
            for (int u4 = 0; u4 < 4; ++u4) {
                float4 kk = *(const float4*)&ks[n * NS + dq * 16 + u4 * 4];
                acc1[u4 * 4 + 0] = fmaf(kk.x, vv, acc1[u4 * 4 + 0]);
                acc1[u4 * 4 + 1] = fmaf(kk.y, vv, acc1[u4 * 4 + 1]);
                acc1[u4 * 4 + 2] = fmaf(kk.z, vv, acc1[u4 * 4 + 2]);
                acc1[u4 * 4 + 3] = fmaf(kk.w, vv, acc1[u4 * 4 + 3]);
            }
        }
        unsigned short ob[16];
#pragma unroll
        for (int u = 0; u < 16; ++u) ob[u] = f2bf(acc1[u]);
        unsigned lb = (unsigned)(e * AS + dq * 16);
        *(uint4*)&att[lb] = make_uint4(pk2(ob[0], ob[1]), pk2(ob[2], ob[3]),
                                       pk2(ob[4], ob[5]), pk2(ob[6], ob[7]));
        *(uint4*)&att[lb + 8] = make_uint4(pk2(ob[8], ob[9]), pk2(ob[10], ob[11]),
                                           pk2(ob[12], ob[13]), pk2(ob[14], ob[15]));
    }
    __syncthreads();
    // ---- phase 4: original yattn MFMA epilogue
    const int lane = tid & 63, wv = tid >> 6;
    const int lq = lane & 15, qd = lane >> 4;
    const int t0 = blockIdx.x * 256 + wv * 64;
    floatx4 acc[4][4];
#pragma unroll
    for (int i = 0; i < 4; ++i)
#pragma unroll
        for (int j = 0; j < 4; ++j) acc[i][j] = (floatx4){0.f, 0.f, 0.f, 0.f};
#pragma unroll
    for (int ks2 = 0; ks2 < 2; ++ks2) {
        short8 av[4], bv[4];
#pragma unroll
        for (int i = 0; i < 4; ++i)
            av[i] = *(const short8*)
                &q[((size_t)(b * 512 + t0 + i * 16 + lq)) * 512 + h * 64 + ks2 * 32 + qd * 8];
#pragma unroll
        for (int j = 0; j < 4; ++j)
            bv[j] = *(const short8*)
                &att[(unsigned)((j * 16 + lq) * AS + ks2 * 32 + qd * 8)];
#pragma unroll
        for (int i = 0; i < 4; ++i)
#pragma unroll
            for (int j = 0; j < 4; ++j)
                acc[i][j] = __builtin_amdgcn_mfma_f32_16x16x32_bf16(
                    av[i], bv[j], acc[i][j], 0, 0, 0);
    }
#pragma unroll
    for (int j = 0; j < 4; ++j) {
        int c = h * 64 + j * 16 + lq;
#pragma unroll
        for (int i = 0; i < 4; ++i) {
            int tb = t0 + i * 16 + qd * 4;
            float vr[4];
#pragma unroll
            for (int r = 0; r < 4; ++r)
                vr[r] = acc[i][j][r] +
                        bf2f(resT[((size_t)(ib * 512 + tb + r)) * 512 + c]);
            float4 o = {vr[0], vr[1], vr[2], vr[3]};
            *(float4*)&out[((size_t)ib * 512 + c) * 512 + tb] = o;
        }
    }
}

extern "C" void kernel_launch(void* const* d_in, const int* in_sizes, int n_in,
                              void* d_out, int out_size, void* d_ws, size_t ws_size,
                              hipStream_t stream) {
    (void)in_sizes; (void)n_in; (void)out_size; (void)ws_size;
    const float* x       = (const float*)d_in[0];
    const float* t       = (const float*)d_in[1];
    const float* cond    = (const float*)d_in[2];
    const float* conv0_w = (const float*)d_in[3];
    const float* conv0_b = (const float*)d_in[4];
    const float* gn0_g   = (const float*)d_in[5];
    const float* gn0_b   = (const float*)d_in[6];
    const float* tm_w    = (const float*)d_in[7];
    const float* tm_b    = (const float*)d_in[8];
    const float* conv1_w = (const float*)d_in[9];
    const float* conv1_b = (const float*)d_in[10];
    const float* gn1_g   = (const float*)d_in[11];
    const float* gn1_b   = (const float*)d_in[12];
    const float* res_w   = (const float*)d_in[13];
    const float* res_b   = (const float*)d_in[14];
    const float* ln_x_g  = (const float*)d_in[15];
    const float* ln_x_b  = (const float*)d_in[16];
    const float* ln_c_g  = (const float*)d_in[17];
    const float* ln_c_b  = (const float*)d_in[18];
    const float* q_w     = (const float*)d_in[19];
    const float* q_b     = (const float*)d_in[20];
    const float* k_w     = (const float*)d_in[21];
    const float* k_b     = (const float*)d_in[22];
    const float* v_w     = (const float*)d_in[23];
    const float* v_b     = (const float*)d_in[24];
    const int*   cidx    = (const int*)d_in[25];
    float* out = (float*)d_out;

    char* WS = (char*)d_ws;
    // overlays; high-water ~132.1 MB (134.6 MB proven in R1)
    unsigned short* xTp   = (unsigned short*)(WS + 0);          // [64][516][256]
    unsigned short* h0Tp  = (unsigned short*)(WS + 16908288);   // [64][516][512]
    unsigned short* xlnT  = (unsigned short*)(WS + 16908288);   // after conv1
    float*          kb    = (float*)(WS + 16908288);            // after q gemm
    float*          vb    = (float*)(WS + 27000832);
    unsigned short* h1T   = (unsigned short*)(WS + 50724864);   // [64][512][512]
    unsigned short* qbf   = (unsigned short*)(WS + 50724864);   // after res gemm
    unsigned short* outTb = (unsigned short*)(WS + 84279296);
    unsigned short* wp0   = (unsigned short*)(WS + 117833728);
    unsigned short* wp1   = (unsigned short*)(WS + 119144448);
    unsigned short* wr    = (unsigned short*)(WS + 121765888);
    unsigned short* wq    = (unsigned short*)(WS + 122028032);
    unsigned short* wk    = (unsigned short*)(WS + 122552320);
    unsigned short* wvv   = (unsigned short*)(WS + 123338752);
    float*          ssb   = (float*)(WS + 124125184);
    float*          mt    = (float*)(WS + 124387328);
    unsigned short* cnb   = (unsigned short*)(WS + 124518400);  // [64][77][768] (own region)

    setup_k<<<dim3(13984), dim3(256), 0, stream>>>(
        conv0_w, conv1_w, res_w, q_w, k_w, v_w, t,
        cond, ln_c_g, ln_c_b, cidx,
        wp0, wp1, wr, wq, wk, wvv, mt, xTp, h0Tp, cnb);
    xpose_cvt<<<dim3(8, 4, 64), dim3(256), 0, stream>>>(x, xTp);
    gemm_nt<512><<<dim3(1, 16), dim3(256), 0, stream>>>(mt, tm_w, tm_b, ssb, 64, 1024);
    conv5_mfma<256, true, true><<<dim3(1024), dim3(256), 0, stream>>>(
        xTp, wp0, conv0_b, gn0_g, gn0_b, ssb, h0Tp);
    conv5_mfma<512, false, false><<<dim3(1024), dim3(256), 0, stream>>>(
        h0Tp, wp1, conv1_b, gn1_g, gn1_b, (const float*)nullptr, h1T);
    gemm1_mfma<256, 0, true><<<dim3(128, 8), dim3(256), 0, stream>>>(
        xTp, wr, res_b, (const unsigned short*)nullptr, (const float*)nullptr,
        h1T, (float*)nullptr, (float*)nullptr, outTb, 32768);
    lnrow<<<dim3(1024), dim3(256), 0, stream>>>(outTb, ln_x_g, ln_x_b, cidx, xlnT);
    gemm1_mfma<512, 1, false><<<dim3(128, 8), dim3(256), 0, stream>>>(
        xlnT, wq, q_b, (const unsigned short*)nullptr, (const float*)nullptr,
        (const unsigned short*)nullptr, (float*)nullptr, (float*)nullptr, qbf, 32768);
    gemm1_mfma<768, 2, false><<<dim3(20, 8, 2), dim3(256), 0, stream>>>(
        cnb, wk, k_b, wvv, v_b,
        (const unsigned short*)nullptr, kb, vb, (unsigned short*)nullptr, 4928);
    yattn_fused<<<dim3(2, 8, 64), dim3(256), 0, stream>>>(
        qbf, kb, vb, outTb, cidx, out);
}

// Round 9
// 595.217 us; speedup vs baseline: 1.6521x; 1.6521x over previous
//
#include <hip/hip_runtime.h>
#include <math.h>

#define EPS 1e-5f

typedef __attribute__((ext_vector_type(8))) short short8;
typedef __attribute__((ext_vector_type(4))) float floatx4;

typedef __attribute__((address_space(1))) const void* gas1_t;
typedef __attribute__((address_space(3))) void* las3_t;

__device__ __forceinline__ void glls16(const void* g, void* l) {
    __builtin_amdgcn_global_load_lds((gas1_t)g, (las3_t)l, 16, 0, 0);
}

__device__ __forceinline__ float mishf(float x) {
    float sp = fmaxf(x, 0.0f) + log1pf(expf(-fabsf(x)));
    return x * tanhf(sp);
}
__device__ __forceinline__ unsigned short f2bf(float f) {
    unsigned int u = __float_as_uint(f);
    unsigned int r = (u + 0x7fffu + ((u >> 16) & 1u)) >> 16;
    return (unsigned short)r;
}
__device__ __forceinline__ float bf2f(unsigned short s) {
    return __uint_as_float(((unsigned int)s) << 16);
}
__device__ __forceinline__ unsigned int pk2(unsigned short a, unsigned short b) {
    return (unsigned int)a | ((unsigned int)b << 16);
}

// ================= fused setup: weight packs, cvt, mish, zero pads, lnc ====
__global__ __launch_bounds__(256) void setup_k(
        const float* __restrict__ conv0_w, const float* __restrict__ conv1_w,
        const float* __restrict__ res_w, const float* __restrict__ q_w,
        const float* __restrict__ k_w, const float* __restrict__ v_w,
        const float* __restrict__ t,
        const float* __restrict__ cond,
        const float* __restrict__ lncg, const float* __restrict__ lncb,
        const int* __restrict__ cidx,
        unsigned short* __restrict__ wp0, unsigned short* __restrict__ wp1,
        unsigned short* __restrict__ wr, unsigned short* __restrict__ wq,
        unsigned short* __restrict__ wk, unsigned short* __restrict__ wvv,
        float* __restrict__ mt,
        unsigned short* __restrict__ xTp, unsigned short* __restrict__ h0Tp,
        unsigned short* __restrict__ cn) {
    __shared__ float r1[4], r2[4], mv[2];
    const int blk = blockIdx.x, tid = threadIdx.x;
    if (blk < 2560) {                       // pack conv0_w -> wp0 [kk][co][ci]
        int o = blk * 256 + tid;
        int ci = o & 255, co = (o >> 8) & 511, kk = o >> 17;
        wp0[o] = f2bf(conv0_w[((size_t)co * 256 + ci) * 5 + kk]);
    } else if (blk < 7680) {                // pack conv1_w -> wp1
        int o = (blk - 2560) * 256 + tid;
        int ci = o & 511, co = (o >> 9) & 511, kk = o >> 18;
        wp1[o] = f2bf(conv1_w[((size_t)co * 512 + ci) * 5 + kk]);
    } else if (blk < 7808) {                // res_w cvt
        int i = (blk - 7680) * 256 + tid;
        float4 f = *(const float4*)&res_w[(size_t)i * 4];
        *(uint2*)&wr[(size_t)i * 4] =
            make_uint2(pk2(f2bf(f.x), f2bf(f.y)), pk2(f2bf(f.z), f2bf(f.w)));
    } else if (blk < 8064) {                // q_w cvt
        int i = (blk - 7808) * 256 + tid;
        float4 f = *(const float4*)&q_w[(size_t)i * 4];
        *(uint2*)&wq[(size_t)i * 4] =
            make_uint2(pk2(f2bf(f.x), f2bf(f.y)), pk2(f2bf(f.z), f2bf(f.w)));
    } else if (blk < 8448) {                // k_w cvt
        int i = (blk - 8064) * 256 + tid;
        float4 f = *(const float4*)&k_w[(size_t)i * 4];
        *(uint2*)&wk[(size_t)i * 4] =
            make_uint2(pk2(f2bf(f.x), f2bf(f.y)), pk2(f2bf(f.z), f2bf(f.w)));
    } else if (blk < 8832) {                // v_w cvt
        int i = (blk - 8448) * 256 + tid;
        float4 f = *(const float4*)&v_w[(size_t)i * 4];
        *(uint2*)&wvv[(size_t)i * 4] =
            make_uint2(pk2(f2bf(f.x), f2bf(f.y)), pk2(f2bf(f.z), f2bf(f.w)));
    } else if (blk < 8960) {                // mish(t)
        int i = (blk - 8832) * 256 + tid;
        mt[i] = mishf(t[i]);
    } else if (blk < 8992) {                // zero xTp pad rows
        int idx = (blk - 8960) * 256 + tid;     // 8192 uint4 stores
        int u = idx * 8;
        int c = u & 255, r4 = (u >> 8) & 3, b = u >> 10;
        int row = (r4 < 2) ? r4 : (512 + r4);
        *(uint4*)&xTp[((size_t)b * 516 + row) * 256 + c] = make_uint4(0, 0, 0, 0);
    } else if (blk < 9056) {                // zero h0Tp pad rows
        int idx = (blk - 8992) * 256 + tid;     // 16384 uint4 stores
        int u = idx * 8;
        int c = u & 511, r4 = (u >> 9) & 3, b = u >> 11;
        int row = (r4 < 2) ? r4 : (512 + r4);
        *(uint4*)&h0Tp[((size_t)b * 516 + row) * 512 + c] = make_uint4(0, 0, 0, 0);
    } else {                                // lnc: LayerNorm cond rows -> cnb
        int bn = blk - 9056;
        int b = bn / 77, n = bn - b * 77;
        int ib = cidx[b];
        const float* src = cond + ((size_t)ib * 77 + n) * 768;
        float v[3];
        float s = 0.f, s2 = 0.f;
#pragma unroll
        for (int i = 0; i < 3; ++i) {
            v[i] = src[tid + i * 256];
            s += v[i]; s2 += v[i] * v[i];
        }
#pragma unroll
        for (int o = 32; o > 0; o >>= 1) {
            s += __shfl_xor(s, o, 64);
            s2 += __shfl_xor(s2, o, 64);
        }
        if ((tid & 63) == 0) { r1[tid >> 6] = s; r2[tid >> 6] = s2; }
        __syncthreads();
        if (tid == 0) {
            float ts = r1[0] + r1[1] + r1[2] + r1[3];
            float ts2 = r2[0] + r2[1] + r2[2] + r2[3];
            float m = ts * (1.f / 768.f);
            float var = ts2 * (1.f / 768.f) - m * m;
            mv[0] = m; mv[1] = rsqrtf(var + EPS);
        }
        __syncthreads();
        float m = mv[0], rs = mv[1];
        unsigned short* dst = cn + ((size_t)b * 77 + n) * 768;
#pragma unroll
        for (int i = 0; i < 3; ++i) {
            int c = tid + i * 256;
            dst[c] = f2bf((v[i] - m) * rs * lncg[c] + lncb[c]);
        }
    }
}

// ------------- x [b][ci][l] fp32 -> xTp [b][516][256] bf16 (rows 2..513)
__global__ __launch_bounds__(256) void xpose_cvt(const float* __restrict__ x,
        unsigned short* __restrict__ xT) {
    __shared__ float tile[64][68];
    const int tid = threadIdx.x;
    const int l0 = blockIdx.x * 64, c0 = blockIdx.y * 64, b = blockIdx.z;
    for (int idx = tid; idx < 64 * 16; idx += 256) {
        int cr = idx >> 4, lc = (idx & 15) * 4;
        float4 f = *(const float4*)&x[((size_t)b * 256 + c0 + cr) * 512 + l0 + lc];
        tile[cr][lc] = f.x; tile[cr][lc + 1] = f.y;
        tile[cr][lc + 2] = f.z; tile[cr][lc + 3] = f.w;
    }
    __syncthreads();
    for (int idx = tid; idx < 64 * 16; idx += 256) {
        int lr = idx >> 4, cc = (idx & 15) * 4;
        *(uint2*)&xT[((size_t)b * 516 + 2 + l0 + lr) * 256 + c0 + cc] =
            make_uint2(pk2(f2bf(tile[cc][lr]), f2bf(tile[cc + 1][lr])),
                       pk2(f2bf(tile[cc + 2][lr]), f2bf(tile[cc + 3][lr])));
    }
}

// ------------------------------------------- fp32 NT GEMM (ss only, tiny)
template<int KD>
__global__ __launch_bounds__(256) void gemm_nt(const float* __restrict__ A,
        const float* __restrict__ W, const float* __restrict__ bias,
        float* __restrict__ C, int M, int N) {
    constexpr int ST = 20;
    __shared__ __align__(16) float As[64 * ST];
    __shared__ __align__(16) float Ws[64 * ST];
    const int tid = threadIdx.x;
    const int r0 = blockIdx.x * 64, c0 = blockIdx.y * 64;
    const int tx = tid & 15, ty = tid >> 4;
    const int lrow = tid >> 2, lk = (tid & 3) * 4;
    float acc[4][4];
#pragma unroll
    for (int i = 0; i < 4; ++i)
#pragma unroll
        for (int j = 0; j < 4; ++j) acc[i][j] = 0.f;
    for (int k0 = 0; k0 < KD; k0 += 16) {
        __syncthreads();
        *(float4*)&As[lrow * ST + lk] =
            *(const float4*)&A[(size_t)(r0 + lrow) * KD + k0 + lk];
        *(float4*)&Ws[lrow * ST + lk] =
            *(const float4*)&W[(size_t)(c0 + lrow) * KD + k0 + lk];
        __syncthreads();
#pragma unroll
        for (int kk = 0; kk < 16; kk += 4) {
            float4 av[4], wv[4];
#pragma unroll
            for (int i = 0; i < 4; ++i)
                av[i] = *(const float4*)&As[(ty + 16 * i) * ST + kk];
#pragma unroll
            for (int j = 0; j < 4; ++j)
                wv[j] = *(const float4*)&Ws[(tx + 16 * j) * ST + kk];
#pragma unroll
            for (int i = 0; i < 4; ++i)
#pragma unroll
                for (int j = 0; j < 4; ++j) {
                    acc[i][j] = fmaf(av[i].x, wv[j].x, acc[i][j]);
                    acc[i][j] = fmaf(av[i].y, wv[j].y, acc[i][j]);
                    acc[i][j] = fmaf(av[i].z, wv[j].z, acc[i][j]);
                    acc[i][j] = fmaf(av[i].w, wv[j].w, acc[i][j]);
                }
        }
    }
#pragma unroll
    for (int j = 0; j < 4; ++j) {
        int c = c0 + tx + 16 * j;
        float bv = bias[c];
#pragma unroll
        for (int i = 0; i < 4; ++i)
            C[(size_t)(r0 + ty + 16 * i) * N + c] = acc[i][j] + bv;
    }
}

// ====== MFMA conv (KS=5), padded input, prefetch double-buffer, fused GN ===
// R9: loop = R1/R6-exact. Grid (8,2,64) with co0 on x: the 8 co-siblings
// sharing an X-tile get CONSECUTIVE block ids -> spread across all 8 XCDs
// (R6's (2,8,64) spread them over 4; R8's same-XCD grouping was 2x WORSE ->
// measured trend: more XCD spread of lockstep demand = faster).
template<int CI, bool FILM, bool OPAD>
__global__ __launch_bounds__(256) void conv5_mfma(
        const unsigned short* __restrict__ xb,
        const unsigned short* __restrict__ wp,
        const float* __restrict__ bias,
        const float* __restrict__ gam, const float* __restrict__ bet,
        const float* __restrict__ ss,
        unsigned short* __restrict__ outT) {
    constexpr int NC = CI / 32;
    __shared__ __align__(16) unsigned short xs[2][260 * 32];
    __shared__ __align__(16) unsigned short wsm[2][5 * 64 * 32];
    __shared__ float sgam[64], sbet[64], sbias[64], sscale[64], sshift[64];

    const int tid = threadIdx.x;
    const int co0 = blockIdx.x * 64;         // x fastest -> siblings adjacent
    const int l0 = blockIdx.y * 256;
    const int b = blockIdx.z;
    const int lane = tid & 63;
    const int wv = tid >> 6;
    const int lq = lane & 15, qd = lane >> 4;
    const int wn = wv * 64;

    if (tid < 64) {
        int co = co0 + tid;
        sbias[tid] = bias[co];
        sgam[tid] = gam[co];
        sbet[tid] = bet[co];
        if (FILM) {
            sscale[tid] = ss[(size_t)b * 1024 + co];
            sshift[tid] = ss[(size_t)b * 1024 + 512 + co];
        }
    }

    const unsigned short* gxb = xb + ((size_t)b * 516 + l0) * CI;
    const unsigned short* gwb = wp + (size_t)co0 * CI;

    // ---- staging pointers; advance +32 shorts per chunk
    const unsigned short* xsp[5];
    const unsigned short* wsp[5];
    unsigned sdo[5];
#pragma unroll
    for (int it = 0; it < 5; ++it) {
        int task = it * 256 + tid;
        {
            int ri = task >> 2, pos = task & 3;
            int seg = pos ^ ((ri >> 1) & 3);
            xsp[it] = gxb + (size_t)ri * CI + seg * 8;
        }
        {
            int kk = task >> 8, r = task & 255;
            int col = r >> 2, pos = r & 3;
            int seg = pos ^ ((col >> 1) & 3);
            wsp[it] = gwb + ((size_t)kk * 512 + col) * CI + seg * 8;
        }
        sdo[it] = (unsigned)(it * 256 + wn) * 8;
    }
    const bool xv4 = tid < 16;   // only x-stage it==4 is partially valid

    auto stage = [&](int buf) {
#pragma unroll
        for (int it = 0; it < 5; ++it) {
            if (it < 4 || xv4) glls16(xsp[it], &xs[buf][sdo[it]]);
            xsp[it] += 32;
        }
#pragma unroll
        for (int it = 0; it < 5; ++it) {
            glls16(wsp[it], &wsm[buf][sdo[it]]);
            wsp[it] += 32;
        }
    };

    // ---- precomputed LDS fragment byte offsets (loop-invariant)
    unsigned bvo[5][4], avo[5][4];
#pragma unroll
    for (int kk = 0; kk < 5; ++kk) {
#pragma unroll
        for (int j = 0; j < 4; ++j) {
            int row = wn + j * 16 + lq + kk;
            int pos = qd ^ ((row >> 1) & 3);
            bvo[kk][j] = (unsigned)(row * 32 + pos * 8) * 2u;
        }
#pragma unroll
        for (int i = 0; i < 4; ++i) {
            int crow = i * 16 + lq;
            int pos = qd ^ ((crow >> 1) & 3);
            avo[kk][i] = (unsigned)(kk * 2048 + crow * 32 + pos * 8) * 2u;
        }
    }

    floatx4 acc[4][4];
#pragma unroll
    for (int i = 0; i < 4; ++i)
#pragma unroll
        for (int j = 0; j < 4; ++j) acc[i][j] = (floatx4){0.f, 0.f, 0.f, 0.f};

    auto compute = [&](int buf) {
        const char* xr = (const char*)xs[buf];
        const char* wr_ = (const char*)wsm[buf];
#pragma unroll
        for (int kk = 0; kk < 5; ++kk) {
            short8 bvf[4];
#pragma unroll
            for (int j = 0; j < 4; ++j)
                bvf[j] = *(const short8*)(xr + bvo[kk][j]);
#pragma unroll
            for (int i = 0; i < 4; ++i) {
                short8 av = *(const short8*)(wr_ + avo[kk][i]);
#pragma unroll
                for (int j = 0; j < 4; ++j)
                    acc[i][j] = __builtin_amdgcn_mfma_f32_16x16x32_bf16(
                        av, bvf[j], acc[i][j], 0, 0, 0);
            }
        }
    };

    stage(0);
    __syncthreads();
#pragma unroll 1
    for (int c = 0; c < NC; c += 2) {
        stage(1);
        compute(0);
        __syncthreads();
        if (c + 2 < NC) stage(0);
        compute(1);
        __syncthreads();
    }

    // ---- fused epilogue: bias, GN stats over 64 co per l, FiLM, mish, bf16
    float m_[4], rs_[4];
#pragma unroll
    for (int j = 0; j < 4; ++j) {
        float s1 = 0.f, s2 = 0.f;
#pragma unroll
        for (int i = 0; i < 4; ++i) {
            float4 bv4 = *(const float4*)&sbias[i * 16 + qd * 4];
            float ba[4] = {bv4.x, bv4.y, bv4.z, bv4.w};
#pragma unroll
            for (int r = 0; r < 4; ++r) {
                float v = acc[i][j][r] + ba[r];
                acc[i][j][r] = v;
                s1 += v; s2 += v * v;
            }
        }
        s1 += __shfl_xor(s1, 16, 64); s2 += __shfl_xor(s2, 16, 64);
        s1 += __shfl_xor(s1, 32, 64); s2 += __shfl_xor(s2, 32, 64);
        float mean = s1 * (1.f / 64.f);
        float var = s2 * (1.f / 64.f) - mean * mean;
        m_[j] = mean; rs_[j] = rsqrtf(var + EPS);
    }
#pragma unroll
    for (int j = 0; j < 4; ++j) {
        int l = l0 + wn + j * 16 + lq;
        size_t rowbase = OPAD ? (((size_t)b * 516 + 2 + l) * 512 + co0)
                              : (((size_t)b * 512 + l) * 512 + co0);
#pragma unroll
        for (int i = 0; i < 4; ++i) {
            float4 g4 = *(const float4*)&sgam[i * 16 + qd * 4];
            float4 b4 = *(const float4*)&sbet[i * 16 + qd * 4];
            float ga[4] = {g4.x, g4.y, g4.z, g4.w};
            float be[4] = {b4.x, b4.y, b4.z, b4.w};
            float sa[4] = {0, 0, 0, 0}, sh[4] = {0, 0, 0, 0};
            if (FILM) {
                float4 s4 = *(const float4*)&sscale[i * 16 + qd * 4];
                float4 h4 = *(const float4*)&sshift[i * 16 + qd * 4];
                sa[0] = s4.x; sa[1] = s4.y; sa[2] = s4.z; sa[3] = s4.w;
                sh[0] = h4.x; sh[1] = h4.y; sh[2] = h4.z; sh[3] = h4.w;
            }
            unsigned short o[4];
#pragma unroll
            for (int r = 0; r < 4; ++r) {
                float v = (acc[i][j][r] - m_[j]) * rs_[j] * ga[r] + be[r];
                if (FILM) v = v * (1.f + sa[r]) + sh[r];
                o[r] = f2bf(mishf(v));
            }
            *(uint2*)&outT[rowbase + i * 16 + qd * 4] =
                make_uint2(pk2(o[0], o[1]), pk2(o[2], o[3]));
        }
    }
}

// ====== generic MFMA GEMM, prefetch double-buffer =========================
// EPI 0=RES(add h1T dense, write outTb bf16); 1=QSM(softmax/head); 2=KV fp32
// PADA: A rows live in [b][516][KD] at row 2+t
// EPI==2 supports merged dual-weight dispatch via blockIdx.z.
template<int KD, int EPI, bool PADA>
__global__ __launch_bounds__(256) void gemm1_mfma(
        const unsigned short* __restrict__ A,
        const unsigned short* __restrict__ W,
        const float* __restrict__ bias,
        const unsigned short* __restrict__ W2,
        const float* __restrict__ bias2,
        const unsigned short* __restrict__ addT,
        float* __restrict__ outF,
        float* __restrict__ outF2,
        unsigned short* __restrict__ outB,
        int Mreal) {
    constexpr int NC = KD / 32;
    __shared__ __align__(16) unsigned short xs[2][256 * 32];
    __shared__ __align__(16) unsigned short wsm[2][64 * 32];
    __shared__ float sbias[64];
    const int tid = threadIdx.x;
    const int m0 = blockIdx.x * 256;
    const int n0 = blockIdx.y * 64;
    const int lane = tid & 63;
    const int wv = tid >> 6;
    const int lq = lane & 15, qd = lane >> 4;
    const int wn = wv * 64;

    const unsigned short* Wu = W;
    const float* biasu = bias;
    float* outFu = outF;
    if (EPI == 2 && blockIdx.z == 1) { Wu = W2; biasu = bias2; outFu = outF2; }

    if (tid < 64) sbias[tid] = biasu[n0 + tid];

    const size_t arow0 = PADA ? ((size_t)(m0 >> 9) * 516 + 2 + (m0 & 511))
                              : (size_t)m0;
    const unsigned short* gA = A + arow0 * KD;
    const unsigned short* gW = Wu + (size_t)n0 * KD;

    // ---- precomputed staging pointers
    const unsigned short* xp[4];
#pragma unroll
    for (int it = 0; it < 4; ++it) {
        int task = it * 256 + tid;
        int ri = task >> 2, pos = task & 3;
        int seg = pos ^ ((ri >> 1) & 3);
        xp[it] = gA + (size_t)ri * KD + seg * 8;
    }
    const unsigned short* wpq;
    {
        int col = tid >> 2, pos = tid & 3;
        int seg = pos ^ ((col >> 1) & 3);
        wpq = gW + (size_t)col * KD + seg * 8;
    }

    auto stage = [&](int buf) {
#pragma unroll
        for (int it = 0; it < 4; ++it) {
            glls16(xp[it], &xs[buf][(unsigned)(it * 256 + wn) * 8]);
            xp[it] += 32;
        }
        glls16(wpq, &wsm[buf][(unsigned)wn * 8]);
        wpq += 32;
    };

    // ---- precomputed LDS fragment byte offsets
    unsigned bvo[4], avo[4];
#pragma unroll
    for (int j = 0; j < 4; ++j) {
        int row = wn + j * 16 + lq;
        int pos = qd ^ ((row >> 1) & 3);
        bvo[j] = (unsigned)(row * 32 + pos * 8) * 2u;
    }
#pragma unroll
    for (int i = 0; i < 4; ++i) {
        int crow = i * 16 + lq;
        int pos = qd ^ ((crow >> 1) & 3);
        avo[i] = (unsigned)(crow * 32 + pos * 8) * 2u;
    }

    floatx4 acc[4][4];
#pragma unroll
    for (int i = 0; i < 4; ++i)
#pragma unroll
        for (int j = 0; j < 4; ++j) acc[i][j] = (floatx4){0.f, 0.f, 0.f, 0.f};

    auto compute = [&](int buf) {
        const char* xr = (const char*)xs[buf];
        const char* wr_ = (const char*)wsm[buf];
        short8 bvf[4];
#pragma unroll
        for (int j = 0; j < 4; ++j)
            bvf[j] = *(const short8*)(xr + bvo[j]);
#pragma unroll
        for (int i = 0; i < 4; ++i) {
            short8 av = *(const short8*)(wr_ + avo[i]);
#pragma unroll
            for (int j = 0; j < 4; ++j)
                acc[i][j] = __builtin_amdgcn_mfma_f32_16x16x32_bf16(
                    av, bvf[j], acc[i][j], 0, 0, 0);
        }
    };

    stage(0);
    __syncthreads();
#pragma unroll 1
    for (int c = 0; c < NC; c += 2) {
        stage(1);
        compute(0);
        __syncthreads();
        if (c + 2 < NC) stage(0);
        compute(1);
        __syncthreads();
    }

#pragma unroll
    for (int i = 0; i < 4; ++i) {
        float4 bv4 = *(const float4*)&sbias[i * 16 + qd * 4];
        float ba[4] = {bv4.x, bv4.y, bv4.z, bv4.w};
#pragma unroll
        for (int j = 0; j < 4; ++j)
#pragma unroll
            for (int r = 0; r < 4; ++r) acc[i][j][r] += ba[r];
    }
    if (EPI == 0) {  // RES
#pragma unroll
        for (int j = 0; j < 4; ++j) {
            int m = m0 + wn + j * 16 + lq;
#pragma unroll
            for (int i = 0; i < 4; ++i) {
                int n = n0 + i * 16 + qd * 4;
                uint2 hv = *(const uint2*)&addT[(size_t)m * 512 + n];
                float vr[4];
                vr[0] = acc[i][j][0] + bf2f((unsigned short)(hv.x & 0xffff));
                vr[1] = acc[i][j][1] + bf2f((unsigned short)(hv.x >> 16));
                vr[2] = acc[i][j][2] + bf2f((unsigned short)(hv.y & 0xffff));
                vr[3] = acc[i][j][3] + bf2f((unsigned short)(hv.y >> 16));
                *(uint2*)&outB[(size_t)m * 512 + n] =
                    make_uint2(pk2(f2bf(vr[0]), f2bf(vr[1])),
                               pk2(f2bf(vr[2]), f2bf(vr[3])));
            }
        }
    } else if (EPI == 1) {  // QSM
#pragma unroll
        for (int j = 0; j < 4; ++j) {
            float mx = -3.4e38f;
#pragma unroll
            for (int i = 0; i < 4; ++i)
#pragma unroll
                for (int r = 0; r < 4; ++r) mx = fmaxf(mx, acc[i][j][r]);
            mx = fmaxf(mx, __shfl_xor(mx, 16, 64));
            mx = fmaxf(mx, __shfl_xor(mx, 32, 64));
            float s = 0.f;
#pragma unroll
            for (int i = 0; i < 4; ++i)
#pragma unroll
                for (int r = 0; r < 4; ++r) {
                    float e = expf(acc[i][j][r] - mx);
                    acc[i][j][r] = e; s += e;
                }
            s += __shfl_xor(s, 16, 64);
            s += __shfl_xor(s, 32, 64);
            float inv = 1.f / s;
            int m = m0 + wn + j * 16 + lq;
#pragma unroll
            for (int i = 0; i < 4; ++i) {
                *(uint2*)&outB[(size_t)m * 512 + n0 + i * 16 + qd * 4] =
                    make_uint2(pk2(f2bf(acc[i][j][0] * inv), f2bf(acc[i][j][1] * inv)),
                               pk2(f2bf(acc[i][j][2] * inv), f2bf(acc[i][j][3] * inv)));
            }
        }
    } else {  // KV
#pragma unroll
        for (int j = 0; j < 4; ++j) {
            int m = m0 + wn + j * 16 + lq;
            if (m < Mreal) {
#pragma unroll
                for (int i = 0; i < 4; ++i) {
                    float4 o = {acc[i][j][0], acc[i][j][1], acc[i][j][2], acc[i][j][3]};
                    *(float4*)&outFu[(size_t)m * 512 + n0 + i * 16 + qd * 4] = o;
                }
            }
        }
    }
}

// ---------- row LayerNorm of outTb[cidx[b]] (512 bf16) -> xlnT bf16
__global__ __launch_bounds__(256) void lnrow(const unsigned short* __restrict__ src,
        const float* __restrict__ g, const float* __restrict__ be,
        const int* __restrict__ cidx, unsigned short* __restrict__ dst) {
    const int tid = threadIdx.x;
    const int lane = tid & 63, wv = tid >> 6;
    const int row0 = blockIdx.x * 32 + wv * 8;
    for (int rr = 0; rr < 8; ++rr) {
        int m = row0 + rr;
        int b = m >> 9, t = m & 511;
        int ib = cidx[b];
        const unsigned short* sp = &src[((size_t)ib * 512 + t) * 512 + lane * 8];
        short8 u = *(const short8*)sp;
        float v[8];
        float s1 = 0.f, s2 = 0.f;
#pragma unroll
        for (int k = 0; k < 8; ++k) {
            v[k] = bf2f(((const unsigned short*)&u)[k]);
            s1 += v[k]; s2 += v[k] * v[k];
        }
#pragma unroll
        for (int o = 32; o > 0; o >>= 1) {
            s1 += __shfl_xor(s1, o, 64);
            s2 += __shfl_xor(s2, o, 64);
        }
        float mean = s1 * (1.f / 512.f);
        float var = s2 * (1.f / 512.f) - mean * mean;
        float rs = rsqrtf(var + EPS);
        float4 g0 = *(const float4*)&g[lane * 8];
        float4 g1 = *(const float4*)&g[lane * 8 + 4];
        float4 b0 = *(const float4*)&be[lane * 8];
        float4 b1 = *(const float4*)&be[lane * 8 + 4];
        float ga[8] = {g0.x, g0.y, g0.z, g0.w, g1.x, g1.y, g1.z, g1.w};
        float ba[8] = {b0.x, b0.y, b0.z, b0.w, b1.x, b1.y, b1.z, b1.w};
        unsigned short o8[8];
#pragma unroll
        for (int k = 0; k < 8; ++k)
            o8[k] = f2bf((v[k] - mean) * rs * ga[k] + ba[k]);
        *(uint4*)&dst[(size_t)m * 512 + lane * 8] =
            make_uint4(pk2(o8[0], o8[1]), pk2(o8[2], o8[3]),
                       pk2(o8[4], o8[5]), pk2(o8[6], o8[7]));
    }
}

// --- attnT[b,h,e,d] = sum_n ksm(k)[b,n,h*64+d] * v[b,n,h*64+e], k-softmax fused
__global__ __launch_bounds__(256) void attn_k(const float* __restrict__ k,
        const float* __restrict__ v, unsigned short* __restrict__ attnT) {
    constexpr int NS = 68;
    __shared__ __align__(16) float ks[77 * NS];
    __shared__ __align__(16) float vs[77 * NS];
    __shared__ float red[2][256];
    const int tid = threadIdx.x;
    const int b = blockIdx.x >> 3, h = blockIdx.x & 7;
    for (int idx = tid; idx < 77 * 16; idx += 256) {
        int n = idx >> 4, dq2 = (idx & 15) * 4;
        *(float4*)&ks[n * NS + dq2] =
            *(const float4*)&k[((size_t)b * 77 + n) * 512 + h * 64 + dq2];
        *(float4*)&vs[n * NS + dq2] =
            *(const float4*)&v[((size_t)b * 77 + n) * 512 + h * 64 + dq2];
    }
    __syncthreads();
    // fused k-softmax over n per d column (d = tid&63, 4 threads/column)
    {
        const int d = tid & 63, grp = tid >> 6;
        float mx = -3.4e38f;
        for (int n = grp; n < 77; n += 4) mx = fmaxf(mx, ks[n * NS + d]);
        red[0][grp * 64 + d] = mx;
        __syncthreads();
        mx = fmaxf(fmaxf(red[0][d], red[0][64 + d]),
                   fmaxf(red[0][128 + d], red[0][192 + d]));
        float s = 0.f;
        for (int n = grp; n < 77; n += 4) {
            float e = expf(ks[n * NS + d] - mx);
            ks[n * NS + d] = e; s += e;
        }
        red[1][grp * 64 + d] = s;
        __syncthreads();
        float inv = 1.f / (red[1][d] + red[1][64 + d] + red[1][128 + d] + red[1][192 + d]);
        for (int n = grp; n < 77; n += 4) ks[n * NS + d] *= inv;
    }
    __syncthreads();
    const int e = tid & 63, dq = tid >> 6;
    float acc[16];
#pragma unroll
    for (int u = 0; u < 16; ++u) acc[u] = 0.f;
    for (int n = 0; n < 77; ++n) {
        float vv = vs[n * NS + e];
#pragma unroll
        for (int u4 = 0; u4 < 4; ++u4) {
            float4 kk = *(const float4*)&ks[n * NS + dq * 16 + u4 * 4];
            acc[u4 * 4 + 0] = fmaf(kk.x, vv, acc[u4 * 4 + 0]);
            acc[u4 * 4 + 1] = fmaf(kk.y, vv, acc[u4 * 4 + 1]);
            acc[u4 * 4 + 2] = fmaf(kk.z, vv, acc[u4 * 4 + 2]);
            acc[u4 * 4 + 3] = fmaf(kk.w, vv, acc[u4 * 4 + 3]);
        }
    }
    unsigned short ob[16];
#pragma unroll
    for (int u = 0; u < 16; ++u) ob[u] = f2bf(acc[u]);
    size_t base = (((size_t)b * 8 + h) * 64 + e) * 64 + dq * 16;
    *(uint4*)&attnT[base] = make_uint4(pk2(ob[0], ob[1]), pk2(ob[2], ob[3]),
                                       pk2(ob[4], ob[5]), pk2(ob[6], ob[7]));
    *(uint4*)&attnT[base + 8] = make_uint4(pk2(ob[8], ob[9]), pk2(ob[10], ob[11]),
                                           pk2(ob[12], ob[13]), pk2(ob[14], ob[15]));
}

// ---- FINAL: out[ib, c, t] = bf2f(resT[..]) + (q @ attnT); no atomics
__global__ __launch_bounds__(256) void yattn_final(
        const unsigned short* __restrict__ q,
        const unsigned short* __restrict__ at,
        const unsigned short* __restrict__ resT,
        const int* __restrict__ cidx, float* __restrict__ out) {
    const int tid = threadIdx.x;
    const int lane = tid & 63, wv = tid >> 6;
    const int lq = lane & 15, qd = lane >> 4;
    const int t0 = blockIdx.x * 256 + wv * 64;
    const int h = blockIdx.y, b = blockIdx.z;
    const int ib = cidx[b];
    floatx4 acc[4][4];
#pragma unroll
    for (int i = 0; i < 4; ++i)
#pragma unroll
        for (int j = 0; j < 4; ++j) acc[i][j] = (floatx4){0.f, 0.f, 0.f, 0.f};
#pragma unroll
    for (int ks = 0; ks < 2; ++ks) {
        short8 av[4], bv[4];
#pragma unroll
        for (int i = 0; i < 4; ++i)
            av[i] = *(const short8*)
                &q[((size_t)(b * 512 + t0 + i * 16 + lq)) * 512 + h * 64 + ks * 32 + qd * 8];
#pragma unroll
        for (int j = 0; j < 4; ++j)
            bv[j] = *(const short8*)
                &at[(((size_t)(b * 8 + h)) * 64 + j * 16 + lq) * 64 + ks * 32 + qd * 8];
#pragma unroll
        for (int i = 0; i < 4; ++i)
#pragma unroll
            for (int j = 0; j < 4; ++j)
                acc[i][j] = __builtin_amdgcn_mfma_f32_16x16x32_bf16(
                    av[i], bv[j], acc[i][j], 0, 0, 0);
    }
#pragma unroll
    for (int j = 0; j < 4; ++j) {
        int c = h * 64 + j * 16 + lq;
#pragma unroll
        for (int i = 0; i < 4; ++i) {
            int tb = t0 + i * 16 + qd * 4;
            float vr[4];
#pragma unroll
            for (int r = 0; r < 4; ++r)
                vr[r] = acc[i][j][r] +
                        bf2f(resT[((size_t)(ib * 512 + tb + r)) * 512 + c]);
            float4 o = {vr[0], vr[1], vr[2], vr[3]};
            *(float4*)&out[((size_t)ib * 512 + c) * 512 + tb] = o;
        }
    }
}

extern "C" void kernel_launch(void* const* d_in, const int* in_sizes, int n_in,
                              void* d_out, int out_size, void* d_ws, size_t ws_size,
                              hipStream_t stream) {
    (void)in_sizes; (void)n_in; (void)out_size; (void)ws_size;
    const float* x       = (const float*)d_in[0];
    const float* t       = (const float*)d_in[1];
    const float* cond    = (const float*)d_in[2];
    const float* conv0_w = (const float*)d_in[3];
    const float* conv0_b = (const float*)d_in[4];
    const float* gn0_g   = (const float*)d_in[5];
    const float* gn0_b   = (const float*)d_in[6];
    const float* tm_w    = (const float*)d_in[7];
    const float* tm_b    = (const float*)d_in[8];
    const float* conv1_w = (const float*)d_in[9];
    const float* conv1_b = (const float*)d_in[10];
    const float* gn1_g   = (const float*)d_in[11];
    const float* gn1_b   = (const float*)d_in[12];
    const float* res_w   = (const float*)d_in[13];
    const float* res_b   = (const float*)d_in[14];
    const float* ln_x_g  = (const float*)d_in[15];
    const float* ln_x_b  = (const float*)d_in[16];
    const float* ln_c_g  = (const float*)d_in[17];
    const float* ln_c_b  = (const float*)d_in[18];
    const float* q_w     = (const float*)d_in[19];
    const float* q_b     = (const float*)d_in[20];
    const float* k_w     = (const float*)d_in[21];
    const float* k_b     = (const float*)d_in[22];
    const float* v_w     = (const float*)d_in[23];
    const float* v_b     = (const float*)d_in[24];
    const int*   cidx    = (const int*)d_in[25];
    float* out = (float*)d_out;

    char* WS = (char*)d_ws;
    // overlays; high-water ~132.1 MB (134.6 MB proven in R1)
    unsigned short* xTp   = (unsigned short*)(WS + 0);          // [64][516][256]
    unsigned short* attnT = (unsigned short*)(WS + 8388608);    // after RES gemm
    unsigned short* h0Tp  = (unsigned short*)(WS + 16908288);   // [64][516][512]
    unsigned short* xlnT  = (unsigned short*)(WS + 16908288);   // after conv1
    float*          kb    = (float*)(WS + 16908288);            // after q gemm
    float*          vb    = (float*)(WS + 27000832);
    unsigned short* h1T   = (unsigned short*)(WS + 50724864);   // [64][512][512]
    unsigned short* qbf   = (unsigned short*)(WS + 50724864);   // after res gemm
    unsigned short* outTb = (unsigned short*)(WS + 84279296);
    unsigned short* wp0   = (unsigned short*)(WS + 117833728);
    unsigned short* wp1   = (unsigned short*)(WS + 119144448);
    unsigned short* wr    = (unsigned short*)(WS + 121765888);
    unsigned short* wq    = (unsigned short*)(WS + 122028032);
    unsigned short* wk    = (unsigned short*)(WS + 122552320);
    unsigned short* wvv   = (unsigned short*)(WS + 123338752);
    float*          ssb   = (float*)(WS + 124125184);
    float*          mt    = (float*)(WS + 124387328);
    unsigned short* cnb   = (unsigned short*)(WS + 124518400);  // [64][77][768] (own region)

    setup_k<<<dim3(13984), dim3(256), 0, stream>>>(
        conv0_w, conv1_w, res_w, q_w, k_w, v_w, t,
        cond, ln_c_g, ln_c_b, cidx,
        wp0, wp1, wr, wq, wk, wvv, mt, xTp, h0Tp, cnb);
    xpose_cvt<<<dim3(8, 4, 64), dim3(256), 0, stream>>>(x, xTp);
    gemm_nt<512><<<dim3(1, 16), dim3(256), 0, stream>>>(mt, tm_w, tm_b, ssb, 64, 1024);
    conv5_mfma<256, true, true><<<dim3(8, 2, 64), dim3(256), 0, stream>>>(
        xTp, wp0, conv0_b, gn0_g, gn0_b, ssb, h0Tp);
    conv5_mfma<512, false, false><<<dim3(8, 2, 64), dim3(256), 0, stream>>>(
        h0Tp, wp1, conv1_b, gn1_g, gn1_b, (const float*)nullptr, h1T);
    gemm1_mfma<256, 0, true><<<dim3(128, 8), dim3(256), 0, stream>>>(
        xTp, wr, res_b, (const unsigned short*)nullptr, (const float*)nullptr,
        h1T, (float*)nullptr, (float*)nullptr, outTb, 32768);
    lnrow<<<dim3(1024), dim3(256), 0, stream>>>(outTb, ln_x_g, ln_x_b, cidx, xlnT);
    gemm1_mfma<512, 1, false><<<dim3(128, 8), dim3(256), 0, stream>>>(
        xlnT, wq, q_b, (const unsigned short*)nullptr, (const float*)nullptr,
        (const unsigned short*)nullptr, (float*)nullptr, (float*)nullptr, qbf, 32768);
    gemm1_mfma<768, 2, false><<<dim3(20, 8, 2), dim3(256), 0, stream>>>(
        cnb, wk, k_b, wvv, v_b,
        (const unsigned short*)nullptr, kb, vb, (unsigned short*)nullptr, 4928);
    attn_k<<<dim3(512), dim3(256), 0, stream>>>(kb, vb, attnT);
    yattn_final<<<dim3(2, 8, 64), dim3(256), 0, stream>>>(qbf, attnT, outTb, cidx, out);
}